// Round 1
// baseline (1233.059 us; speedup 1.0000x reference)
//
#include <hip/hip_runtime.h>
#include <math.h>

namespace {

constexpr int B = 2;
constexpr int N = 8192;
constexpr int PART = 4;
constexpr int CAND = N / PART;          // 2048
constexpr int D = 64;
constexpr float NEGS = 0.2f;
constexpr float BN_INV = 0.9999950000374997f;   // 1/sqrt(1+1e-5)
constexpr float RSQN = 0.011048543456039806f;   // 1/sqrt(8192)

__device__ __forceinline__ float lrelu(float v) { return v > 0.f ? v : NEGS * v; }

// ---------------- prep: transpose + fold BN scale into weights ----------------
struct PrepArgs {
  const float* src[9];
  const float* scale[9];
  float* dst[9];
};

__global__ __launch_bounds__(256) void prep_kernel(PrepArgs a) {
  int mi = blockIdx.x;
  if (mi < 8) {
    const float* S = a.src[mi];
    const float* G = a.scale[mi];
    float* Dst = a.dst[mi];
    bool tr = (mi != 7);                 // W2 (index 7) stays row-major
    for (int i = threadIdx.x; i < D * D; i += 256) {
      int o = i >> 6, c = i & 63;
      float v = S[i];
      if (G) v *= G[o] * BN_INV;
      Dst[tr ? (c * D + o) : i] = v;
    }
  } else {
    // Wd1 [64][3] folded with gd1 into [64][4]
    const float* S = a.src[8];
    const float* G = a.scale[8];
    float* Dst = a.dst[8];
    for (int o = threadIdx.x; o < D; o += 256) {
      float s = G[o] * BN_INV;
      Dst[o * 4 + 0] = S[o * 3 + 0] * s;
      Dst[o * 4 + 1] = S[o * 3 + 1] * s;
      Dst[o * 4 + 2] = S[o * 3 + 2] * s;
      Dst[o * 4 + 3] = 0.f;
    }
  }
}

// ---------------- qkv: x = lrelu(bn(W1@feats)); q/k/v = W{q,k,v}@x, stored [B*N][64] ----------------
__global__ __launch_bounds__(64) void qkv_kernel(
    const float* __restrict__ feats,
    const float* __restrict__ W1Tf, const float* __restrict__ b1,
    const float* __restrict__ WqT, const float* __restrict__ WkT, const float* __restrict__ WvT,
    float* __restrict__ qT, float* __restrict__ kT, float* __restrict__ vT)
{
  __shared__ float scr[64 * 65];
  int tid = threadIdx.x;
  int b = blockIdx.x >> 7;                       // 128 blocks per batch
  int n = (blockIdx.x & 127) * 64 + tid;
  int g = b * N + n;
  const float* fb = feats + (size_t)b * D * N + n;
  float* col = scr + tid * 65;

  float acc[D];
  #pragma unroll
  for (int o = 0; o < D; ++o) acc[o] = 0.f;
  for (int c = 0; c < D; ++c) {
    float xc = fb[(size_t)c * N];
    const float* wr = W1Tf + c * D;
    #pragma unroll
    for (int o = 0; o < D; ++o) acc[o] = fmaf(wr[o], xc, acc[o]);
  }
  #pragma unroll
  for (int o = 0; o < D; ++o) col[o] = lrelu(acc[o] + b1[o]);

  // q
  #pragma unroll
  for (int o = 0; o < D; ++o) acc[o] = 0.f;
  for (int c = 0; c < D; ++c) {
    float xc = col[c];
    const float* wr = WqT + c * D;
    #pragma unroll
    for (int o = 0; o < D; ++o) acc[o] = fmaf(wr[o], xc, acc[o]);
  }
  {
    float* orow = qT + (size_t)g * D;
    #pragma unroll
    for (int o = 0; o < D; ++o) orow[o] = acc[o];
  }
  // k
  #pragma unroll
  for (int o = 0; o < D; ++o) acc[o] = 0.f;
  for (int c = 0; c < D; ++c) {
    float xc = col[c];
    const float* wr = WkT + c * D;
    #pragma unroll
    for (int o = 0; o < D; ++o) acc[o] = fmaf(wr[o], xc, acc[o]);
  }
  {
    float* orow = kT + (size_t)g * D;
    #pragma unroll
    for (int o = 0; o < D; ++o) orow[o] = acc[o];
  }
  // v
  #pragma unroll
  for (int o = 0; o < D; ++o) acc[o] = 0.f;
  for (int c = 0; c < D; ++c) {
    float xc = col[c];
    const float* wr = WvT + c * D;
    #pragma unroll
    for (int o = 0; o < D; ++o) acc[o] = fmaf(wr[o], xc, acc[o]);
  }
  {
    float* orow = vT + (size_t)g * D;
    #pragma unroll
    for (int o = 0; o < D; ++o) orow[o] = acc[o];
  }
}

// ---------------- knn: brute force, 4 candidate partitions, sorted top-16 per (query,partition) ----------------
__global__ __launch_bounds__(256) void knn_kernel(
    const float* __restrict__ pos,
    float* __restrict__ pd, int* __restrict__ pi)
{
  int b = blockIdx.x >> 5;                       // 32 blocks per batch
  int n = (blockIdx.x & 31) * 256 + threadIdx.x;
  int q = b * N + n;
  int p = blockIdx.y;
  const float* px = pos + (size_t)b * 3 * N;     // wave-uniform base -> scalar candidate loads
  const float* py = px + N;
  const float* pz = px + 2 * N;
  float qx = px[n], qy = py[n], qz = pz[n];
  float sqn = qx * qx + qy * qy + qz * qz;

  float d[16];
  int id[16];
  #pragma unroll
  for (int j = 0; j < 16; ++j) { d[j] = 3.4e38f; id[j] = -1; }

  int mbase = p * CAND;
  for (int mm = mbase; mm < mbase + CAND; ++mm) {
    float cx = px[mm], cy = py[mm], cz = pz[mm];           // uniform -> s_load
    float sqm = cx * cx + cy * cy + cz * cz;
    float inn = qx * cx + qy * cy + qz * cz;
    float dist = sqn + sqm - 2.f * inn;
    if (dist < d[15]) {
      bool bj = true;                                       // dist < d[15]
      #pragma unroll
      for (int j = 15; j >= 1; --j) {
        bool bjm1 = dist < d[j - 1];
        d[j]  = bj ? (bjm1 ? d[j - 1]  : dist) : d[j];
        id[j] = bj ? (bjm1 ? id[j - 1] : mm)   : id[j];
        bj = bjm1;
      }
      if (bj) { d[0] = dist; id[0] = mm; }
    }
  }
  float* od = pd + ((size_t)q * PART + p) * 16;
  int* oi = pi + ((size_t)q * PART + p) * 16;
  #pragma unroll
  for (int j = 0; j < 16; ++j) { od[j] = d[j]; oi[j] = id[j]; }
}

// ---------------- merge 4 sorted partition lists -> final 16 neighbor indices ----------------
__global__ __launch_bounds__(256) void merge_kernel(
    const float* __restrict__ pd, const int* __restrict__ pi, int* __restrict__ knn)
{
  int q = blockIdx.x * 256 + threadIdx.x;
  const float* base = pd + (size_t)q * (PART * 16);
  const int* ibase = pi + (size_t)q * (PART * 16);
  int c0 = 0, c1 = 0, c2 = 0, c3 = 0;
  #pragma unroll 1
  for (int r = 0; r < 16; ++r) {
    float d0 = (c0 < 16) ? base[c0]      : 3.5e38f;
    float d1 = (c1 < 16) ? base[16 + c1] : 3.5e38f;
    float d2 = (c2 < 16) ? base[32 + c2] : 3.5e38f;
    float d3 = (c3 < 16) ? base[48 + c3] : 3.5e38f;
    int bp = 0; float bd = d0;
    if (d1 < bd) { bd = d1; bp = 1; }
    if (d2 < bd) { bd = d2; bp = 2; }
    if (d3 < bd) { bd = d3; bp = 3; }
    int sel;
    if (bp == 0)      { sel = ibase[c0];      c0++; }
    else if (bp == 1) { sel = ibase[16 + c1]; c1++; }
    else if (bp == 2) { sel = ibase[32 + c2]; c2++; }
    else              { sel = ibase[48 + c3]; c3++; }
    knn[(size_t)q * 16 + r] = sel;
  }
}

// ---------------- fused main chain: pe -> pos_enc -> a -> softmax -> res -> out ----------------
__global__ __launch_bounds__(64) void fused_kernel(
    const float* __restrict__ pos, const float* __restrict__ feats,
    const int* __restrict__ knn,
    const float* __restrict__ qT, const float* __restrict__ kT, const float* __restrict__ vT,
    const float* __restrict__ Wd1f, const float* __restrict__ bd1,
    const float* __restrict__ Wd2Tf, const float* __restrict__ bd2,
    const float* __restrict__ Wg1Tf, const float* __restrict__ bg1,
    const float* __restrict__ Wg2Tf, const float* __restrict__ bg2,
    const float* __restrict__ W2f, const float* __restrict__ b2,
    float* __restrict__ out)
{
  __shared__ float scr[64 * 65];
  int tid = threadIdx.x;            // 64 threads = 4 points x 16 neighbors
  int kk = tid & 15;
  int pt = tid >> 4;
  int b = blockIdx.x >> 11;                       // 2048 blocks per batch
  int n = (blockIdx.x & 2047) * 4 + pt;
  int gpt = b * N + n;
  int m = knn[(size_t)gpt * 16 + kk];

  const float* pb = pos + (size_t)b * 3 * N;
  float rx = pb[n] - pb[m];
  float ry = pb[N + n] - pb[N + m];
  float rz = pb[2 * N + n] - pb[2 * N + m];

  float* col = scr + tid * 65;      // stride 65: 2-way LDS bank aliasing only (free)

  // pe = lrelu(bn(Wd1 @ rel))  (scale folded into Wd1f)
  #pragma unroll
  for (int o = 0; o < D; ++o) {
    const float4 w = *reinterpret_cast<const float4*>(Wd1f + o * 4);
    float v = w.x * rx + w.y * ry + w.z * rz + bd1[o];
    col[o] = lrelu(v);
  }

  float acc[D];
  // pos_enc = lrelu(bn(Wd2 @ pe))
  #pragma unroll
  for (int o = 0; o < D; ++o) acc[o] = 0.f;
  for (int c = 0; c < D; ++c) {
    float xc = col[c];
    const float* wr = Wd2Tf + c * D;
    #pragma unroll
    for (int o = 0; o < D; ++o) acc[o] = fmaf(wr[o], xc, acc[o]);
  }

  const float* qrow = qT + (size_t)(b * N + n) * D;
  const float* krow = kT + (size_t)(b * N + m) * D;
  const float* vrow = vT + (size_t)(b * N + m) * D;
  float vpe[D];
  #pragma unroll
  for (int o = 0; o < D; ++o) {
    float pv = lrelu(acc[o] + bd2[o]);
    vpe[o] = vrow[o] + pv;
    col[o] = qrow[o] - krow[o] + pv;   // a0
  }

  // a1 = lrelu(bn(Wg1 @ a0))
  #pragma unroll
  for (int o = 0; o < D; ++o) acc[o] = 0.f;
  for (int c = 0; c < D; ++c) {
    float xc = col[c];
    const float* wr = Wg1Tf + c * D;
    #pragma unroll
    for (int o = 0; o < D; ++o) acc[o] = fmaf(wr[o], xc, acc[o]);
  }
  #pragma unroll
  for (int o = 0; o < D; ++o) col[o] = lrelu(acc[o] + bg1[o]);

  // a2 = lrelu(bn(Wg2 @ a1))
  #pragma unroll
  for (int o = 0; o < D; ++o) acc[o] = 0.f;
  for (int c = 0; c < D; ++c) {
    float xc = col[c];
    const float* wr = Wg2Tf + c * D;
    #pragma unroll
    for (int o = 0; o < D; ++o) acc[o] = fmaf(wr[o], xc, acc[o]);
  }

  // softmax over K (16-lane groups) + weighted sum of (v + pos_enc)
  #pragma unroll
  for (int o = 0; o < D; ++o) {
    float t = lrelu(acc[o] + bg2[o]) * RSQN;
    float mx = t;
    mx = fmaxf(mx, __shfl_xor(mx, 1));
    mx = fmaxf(mx, __shfl_xor(mx, 2));
    mx = fmaxf(mx, __shfl_xor(mx, 4));
    mx = fmaxf(mx, __shfl_xor(mx, 8));
    float e = __expf(t - mx);
    float s = e;
    s += __shfl_xor(s, 1);
    s += __shfl_xor(s, 2);
    s += __shfl_xor(s, 4);
    s += __shfl_xor(s, 8);
    float r = (e / s) * vpe[o];
    r += __shfl_xor(r, 1);
    r += __shfl_xor(r, 2);
    r += __shfl_xor(r, 4);
    r += __shfl_xor(r, 8);
    acc[o] = r;                       // res, replicated across the 16 lanes
  }

  // out = lrelu(bn(W2 @ res)) + feats ; each lane writes channels o = kk*4 + j
  const float* fb = feats + (size_t)b * D * N + n;
  float* ob = out + (size_t)b * D * N + n;
  #pragma unroll
  for (int j = 0; j < 4; ++j) {
    int o = kk * 4 + j;
    const float* wrow = W2f + o * D;
    float a = 0.f;
    #pragma unroll
    for (int c = 0; c < D; ++c) a = fmaf(wrow[c], acc[c], a);
    float v = lrelu(a + b2[o]);
    ob[(size_t)o * N] = v + fb[(size_t)o * N];
  }
}

} // namespace

extern "C" void kernel_launch(void* const* d_in, const int* in_sizes, int n_in,
                              void* d_out, int out_size, void* d_ws, size_t ws_size,
                              hipStream_t stream) {
  const float* feats = (const float*)d_in[0];
  const float* pos   = (const float*)d_in[1];
  const float* W1  = (const float*)d_in[3];
  const float* g1  = (const float*)d_in[4];
  const float* b1  = (const float*)d_in[5];
  const float* Wq  = (const float*)d_in[6];
  const float* Wk  = (const float*)d_in[7];
  const float* Wv  = (const float*)d_in[8];
  const float* Wd1 = (const float*)d_in[9];
  const float* gd1 = (const float*)d_in[10];
  const float* bd1 = (const float*)d_in[11];
  const float* Wd2 = (const float*)d_in[12];
  const float* gd2 = (const float*)d_in[13];
  const float* bd2 = (const float*)d_in[14];
  const float* Wg1 = (const float*)d_in[15];
  const float* gg1 = (const float*)d_in[16];
  const float* bg1 = (const float*)d_in[17];
  const float* Wg2 = (const float*)d_in[18];
  const float* gg2 = (const float*)d_in[19];
  const float* bg2 = (const float*)d_in[20];
  const float* W2  = (const float*)d_in[21];
  const float* g2  = (const float*)d_in[22];
  const float* b2  = (const float*)d_in[23];

  float* ws = (float*)d_ws;
  float* W1Tf  = ws;
  float* WqT   = ws + 4096;
  float* WkT   = ws + 8192;
  float* WvT   = ws + 12288;
  float* Wd2Tf = ws + 16384;
  float* Wg1Tf = ws + 20480;
  float* Wg2Tf = ws + 24576;
  float* W2f   = ws + 28672;
  float* Wd1f  = ws + 32768;            // 256
  float* qT = ws + 33024;
  float* kT = qT + (size_t)B * N * D;
  float* vT = kT + (size_t)B * N * D;
  float* pd = vT + (size_t)B * N * D;
  int*   pi = (int*)(pd + (size_t)B * N * PART * 16);
  int*   knn = pi + (size_t)B * N * PART * 16;

  PrepArgs pa;
  pa.src[0] = W1;  pa.scale[0] = g1;      pa.dst[0] = W1Tf;
  pa.src[1] = Wq;  pa.scale[1] = nullptr; pa.dst[1] = WqT;
  pa.src[2] = Wk;  pa.scale[2] = nullptr; pa.dst[2] = WkT;
  pa.src[3] = Wv;  pa.scale[3] = nullptr; pa.dst[3] = WvT;
  pa.src[4] = Wd2; pa.scale[4] = gd2;     pa.dst[4] = Wd2Tf;
  pa.src[5] = Wg1; pa.scale[5] = gg1;     pa.dst[5] = Wg1Tf;
  pa.src[6] = Wg2; pa.scale[6] = gg2;     pa.dst[6] = Wg2Tf;
  pa.src[7] = W2;  pa.scale[7] = g2;      pa.dst[7] = W2f;
  pa.src[8] = Wd1; pa.scale[8] = gd1;     pa.dst[8] = Wd1f;

  hipLaunchKernelGGL(prep_kernel, dim3(9), dim3(256), 0, stream, pa);
  hipLaunchKernelGGL(qkv_kernel, dim3(B * N / 64), dim3(64), 0, stream,
                     feats, W1Tf, b1, WqT, WkT, WvT, qT, kT, vT);
  hipLaunchKernelGGL(knn_kernel, dim3(B * N / 256, PART), dim3(256), 0, stream,
                     pos, pd, pi);
  hipLaunchKernelGGL(merge_kernel, dim3(B * N / 256), dim3(256), 0, stream,
                     pd, pi, knn);
  hipLaunchKernelGGL(fused_kernel, dim3(B * N / 4), dim3(64), 0, stream,
                     pos, feats, knn, qT, kT, vT, Wd1f, bd1, Wd2Tf, bd2,
                     Wg1Tf, bg1, Wg2Tf, bg2, W2f, b2, (float*)d_out);
}

// Round 2
// 487.776 us; speedup vs baseline: 2.5279x; 2.5279x over previous
//
#include <hip/hip_runtime.h>
#include <math.h>

namespace {

constexpr int B = 2;
constexpr int N = 8192;
constexpr int PART = 8;
constexpr int CAND = N / PART;          // 1024
constexpr int BUF = 16;
constexpr int D = 64;
constexpr float NEGS = 0.2f;
constexpr float BN_INV = 0.9999950000374997f;   // 1/sqrt(1+1e-5)
constexpr float RSQN = 0.011048543456039806f;   // 1/sqrt(8192)

__device__ __forceinline__ float lrelu(float v) { return v > 0.f ? v : NEGS * v; }

// ---------------- prep: transpose + fold BN scale into weights ----------------
struct PrepArgs {
  const float* src[9];
  const float* scale[9];
  float* dst[9];
};

__global__ __launch_bounds__(256) void prep_kernel(PrepArgs a) {
  int mi = blockIdx.x;
  if (mi < 8) {
    const float* S = a.src[mi];
    const float* G = a.scale[mi];
    float* Dst = a.dst[mi];
    bool tr = (mi != 7);                 // W2 (index 7) stays row-major
    for (int i = threadIdx.x; i < D * D; i += 256) {
      int o = i >> 6, c = i & 63;
      float v = S[i];
      if (G) v *= G[o] * BN_INV;
      Dst[tr ? (c * D + o) : i] = v;
    }
  } else {
    // Wd1 [64][3] folded with gd1 into [64][4]
    const float* S = a.src[8];
    const float* G = a.scale[8];
    float* Dst = a.dst[8];
    for (int o = threadIdx.x; o < D; o += 256) {
      float s = G[o] * BN_INV;
      Dst[o * 4 + 0] = S[o * 3 + 0] * s;
      Dst[o * 4 + 1] = S[o * 3 + 1] * s;
      Dst[o * 4 + 2] = S[o * 3 + 2] * s;
      Dst[o * 4 + 3] = 0.f;
    }
  }
}

// ---------------- pos4: pack (x,y,z,|p|^2) per point for scalar candidate loads ----------------
__global__ __launch_bounds__(256) void pos4_kernel(
    const float* __restrict__ pos, float* __restrict__ pos4)
{
  int i = blockIdx.x * 256 + threadIdx.x;      // over B*N
  int b = i >> 13;
  int n = i & (N - 1);
  const float* pb = pos + (size_t)b * 3 * N;
  float x = pb[n], y = pb[N + n], z = pb[2 * N + n];
  float4 v = {x, y, z, x * x + y * y + z * z};
  *reinterpret_cast<float4*>(pos4 + (size_t)i * 4) = v;
}

// ---------------- qkv: x = lrelu(bn(W1@feats)); q/k/v = W{q,k,v}@x, stored [B*N][64] ----------------
__global__ __launch_bounds__(64) void qkv_kernel(
    const float* __restrict__ feats,
    const float* __restrict__ W1Tf, const float* __restrict__ b1,
    const float* __restrict__ WqT, const float* __restrict__ WkT, const float* __restrict__ WvT,
    float* __restrict__ qT, float* __restrict__ kT, float* __restrict__ vT)
{
  __shared__ float scr[64 * 65];
  int tid = threadIdx.x;
  int b = blockIdx.x >> 7;                       // 128 blocks per batch
  int n = (blockIdx.x & 127) * 64 + tid;
  int g = b * N + n;
  const float* fb = feats + (size_t)b * D * N + n;
  float* col = scr + tid * 65;

  float acc[D];
  #pragma unroll
  for (int o = 0; o < D; ++o) acc[o] = 0.f;
  for (int c = 0; c < D; ++c) {
    float xc = fb[(size_t)c * N];
    const float* wr = W1Tf + c * D;
    #pragma unroll
    for (int o = 0; o < D; ++o) acc[o] = fmaf(wr[o], xc, acc[o]);
  }
  #pragma unroll
  for (int o = 0; o < D; ++o) col[o] = lrelu(acc[o] + b1[o]);

  // q
  #pragma unroll
  for (int o = 0; o < D; ++o) acc[o] = 0.f;
  for (int c = 0; c < D; ++c) {
    float xc = col[c];
    const float* wr = WqT + c * D;
    #pragma unroll
    for (int o = 0; o < D; ++o) acc[o] = fmaf(wr[o], xc, acc[o]);
  }
  {
    float* orow = qT + (size_t)g * D;
    #pragma unroll
    for (int o = 0; o < D; ++o) orow[o] = acc[o];
  }
  // k
  #pragma unroll
  for (int o = 0; o < D; ++o) acc[o] = 0.f;
  for (int c = 0; c < D; ++c) {
    float xc = col[c];
    const float* wr = WkT + c * D;
    #pragma unroll
    for (int o = 0; o < D; ++o) acc[o] = fmaf(wr[o], xc, acc[o]);
  }
  {
    float* orow = kT + (size_t)g * D;
    #pragma unroll
    for (int o = 0; o < D; ++o) orow[o] = acc[o];
  }
  // v
  #pragma unroll
  for (int o = 0; o < D; ++o) acc[o] = 0.f;
  for (int c = 0; c < D; ++c) {
    float xc = col[c];
    const float* wr = WvT + c * D;
    #pragma unroll
    for (int o = 0; o < D; ++o) acc[o] = fmaf(wr[o], xc, acc[o]);
  }
  {
    float* orow = vT + (size_t)g * D;
    #pragma unroll
    for (int o = 0; o < D; ++o) orow[o] = acc[o];
  }
}

// ---------------- knn: buffered top-16 (WarpSelect-style) per (query, partition) ----------------
__global__ __launch_bounds__(256) void knn_kernel(
    const float* __restrict__ pos4,
    float* __restrict__ pd, int* __restrict__ pi)
{
  __shared__ float bufd[256 * BUF];
  __shared__ int   bufi[256 * BUF];
  int tid = threadIdx.x;
  int b = blockIdx.x >> 5;                       // 32 blocks per batch
  int n = (blockIdx.x & 31) * 256 + tid;
  int q = b * N + n;
  int p = blockIdx.y;
  const float* base = pos4 + (size_t)b * N * 4;
  float4 qp = *reinterpret_cast<const float4*>(base + (size_t)n * 4);

  float d[16];
  int id[16];
  #pragma unroll
  for (int j = 0; j < 16; ++j) { d[j] = 3.4e38f; id[j] = -1; }
  float thr = 3.4e38f;
  int c = 0;

  auto do_merge = [&]() {
    #pragma unroll 1
    for (int t = 0; t < BUF; ++t) {
      if (__all(t >= c)) break;
      float nd = 3.5e38f;
      int ni = -1;
      if (t < c) {
        nd = bufd[tid + (t << 8)];
        ni = bufi[tid + (t << 8)];
      }
      if (nd < d[15]) {
        bool bj = true;
        #pragma unroll
        for (int j = 15; j >= 1; --j) {
          bool bjm1 = nd < d[j - 1];
          d[j]  = bj ? (bjm1 ? d[j - 1]  : nd) : d[j];
          id[j] = bj ? (bjm1 ? id[j - 1] : ni) : id[j];
          bj = bjm1;
        }
        if (bj) { d[0] = nd; id[0] = ni; }
      }
    }
    c = 0;
    thr = d[15];
  };

  int mbase = p * CAND;
  #pragma unroll 1
  for (int m0 = mbase; m0 < mbase + CAND; m0 += 4) {
    #pragma unroll
    for (int u = 0; u < 4; ++u) {
      int mm = m0 + u;
      const float4 cp = *reinterpret_cast<const float4*>(base + (size_t)mm * 4);  // wave-uniform -> s_load
      float inn = qp.x * cp.x + qp.y * cp.y + qp.z * cp.z;
      float dist = fmaf(-2.f, inn, qp.w + cp.w);
      if (dist < thr) {
        bufd[tid + (c << 8)] = dist;
        bufi[tid + (c << 8)] = mm;
        ++c;
      }
    }
    if (__any(c >= BUF - 3)) do_merge();
  }
  do_merge();

  float* od = pd + ((size_t)q * PART + p) * 16;
  int* oi = pi + ((size_t)q * PART + p) * 16;
  #pragma unroll
  for (int j = 0; j < 16; ++j) { od[j] = d[j]; oi[j] = id[j]; }
}

// ---------------- merge stage 1: 4 sorted lists -> 1 sorted list (x2 groups per query) ----------------
__global__ __launch_bounds__(256) void merge4_kernel(
    const float* __restrict__ pd, const int* __restrict__ pi,
    float* __restrict__ pd2, int* __restrict__ pi2)
{
  int i = blockIdx.x * 256 + threadIdx.x;        // over B*N*2
  const float* base = pd + (size_t)i * 64;
  const int* ibase = pi + (size_t)i * 64;
  float* od = pd2 + (size_t)i * 16;
  int* oi = pi2 + (size_t)i * 16;
  int c0 = 0, c1 = 0, c2 = 0, c3 = 0;
  #pragma unroll 1
  for (int r = 0; r < 16; ++r) {
    float d0 = (c0 < 16) ? base[c0]      : 3.5e38f;
    float d1 = (c1 < 16) ? base[16 + c1] : 3.5e38f;
    float d2 = (c2 < 16) ? base[32 + c2] : 3.5e38f;
    float d3 = (c3 < 16) ? base[48 + c3] : 3.5e38f;
    int bp = 0; float bd = d0;
    if (d1 < bd) { bd = d1; bp = 1; }
    if (d2 < bd) { bd = d2; bp = 2; }
    if (d3 < bd) { bd = d3; bp = 3; }
    float sd; int sel;
    if (bp == 0)      { sd = d0; sel = ibase[c0];      c0++; }
    else if (bp == 1) { sd = d1; sel = ibase[16 + c1]; c1++; }
    else if (bp == 2) { sd = d2; sel = ibase[32 + c2]; c2++; }
    else              { sd = d3; sel = ibase[48 + c3]; c3++; }
    od[r] = sd;
    oi[r] = sel;
  }
}

// ---------------- merge stage 2: 2 sorted lists -> final 16 neighbor indices ----------------
__global__ __launch_bounds__(256) void merge2_kernel(
    const float* __restrict__ pd2, const int* __restrict__ pi2, int* __restrict__ knn)
{
  int q = blockIdx.x * 256 + threadIdx.x;        // over B*N
  const float* base = pd2 + (size_t)q * 32;
  const int* ibase = pi2 + (size_t)q * 32;
  int c0 = 0, c1 = 0;
  #pragma unroll 1
  for (int r = 0; r < 16; ++r) {
    float d0 = (c0 < 16) ? base[c0]      : 3.5e38f;
    float d1 = (c1 < 16) ? base[16 + c1] : 3.5e38f;
    int sel;
    if (d1 < d0) { sel = ibase[16 + c1]; c1++; }
    else         { sel = ibase[c0];      c0++; }
    knn[(size_t)q * 16 + r] = sel;
  }
}

// ---------------- fused main chain: pe -> pos_enc -> a -> softmax -> res -> out ----------------
__global__ __launch_bounds__(64) void fused_kernel(
    const float* __restrict__ pos, const float* __restrict__ feats,
    const int* __restrict__ knn,
    const float* __restrict__ qT, const float* __restrict__ kT, const float* __restrict__ vT,
    const float* __restrict__ Wd1f, const float* __restrict__ bd1,
    const float* __restrict__ Wd2Tf, const float* __restrict__ bd2,
    const float* __restrict__ Wg1Tf, const float* __restrict__ bg1,
    const float* __restrict__ Wg2Tf, const float* __restrict__ bg2,
    const float* __restrict__ W2f, const float* __restrict__ b2,
    float* __restrict__ out)
{
  __shared__ float scr[64 * 65];
  int tid = threadIdx.x;            // 64 threads = 4 points x 16 neighbors
  int kk = tid & 15;
  int pt = tid >> 4;
  int b = blockIdx.x >> 11;                       // 2048 blocks per batch
  int n = (blockIdx.x & 2047) * 4 + pt;
  int gpt = b * N + n;
  int m = knn[(size_t)gpt * 16 + kk];

  const float* pb = pos + (size_t)b * 3 * N;
  float rx = pb[n] - pb[m];
  float ry = pb[N + n] - pb[N + m];
  float rz = pb[2 * N + n] - pb[2 * N + m];

  float* col = scr + tid * 65;      // stride 65: 2-way LDS bank aliasing only (free)

  // pe = lrelu(bn(Wd1 @ rel))  (scale folded into Wd1f)
  #pragma unroll
  for (int o = 0; o < D; ++o) {
    const float4 w = *reinterpret_cast<const float4*>(Wd1f + o * 4);
    float v = w.x * rx + w.y * ry + w.z * rz + bd1[o];
    col[o] = lrelu(v);
  }

  float acc[D];
  // pos_enc = lrelu(bn(Wd2 @ pe))
  #pragma unroll
  for (int o = 0; o < D; ++o) acc[o] = 0.f;
  for (int c = 0; c < D; ++c) {
    float xc = col[c];
    const float* wr = Wd2Tf + c * D;
    #pragma unroll
    for (int o = 0; o < D; ++o) acc[o] = fmaf(wr[o], xc, acc[o]);
  }

  const float* qrow = qT + (size_t)(b * N + n) * D;
  const float* krow = kT + (size_t)(b * N + m) * D;
  const float* vrow = vT + (size_t)(b * N + m) * D;
  float vpe[D];
  #pragma unroll
  for (int o = 0; o < D; ++o) {
    float pv = lrelu(acc[o] + bd2[o]);
    vpe[o] = vrow[o] + pv;
    col[o] = qrow[o] - krow[o] + pv;   // a0
  }

  // a1 = lrelu(bn(Wg1 @ a0))
  #pragma unroll
  for (int o = 0; o < D; ++o) acc[o] = 0.f;
  for (int c = 0; c < D; ++c) {
    float xc = col[c];
    const float* wr = Wg1Tf + c * D;
    #pragma unroll
    for (int o = 0; o < D; ++o) acc[o] = fmaf(wr[o], xc, acc[o]);
  }
  #pragma unroll
  for (int o = 0; o < D; ++o) col[o] = lrelu(acc[o] + bg1[o]);

  // a2 = lrelu(bn(Wg2 @ a1))
  #pragma unroll
  for (int o = 0; o < D; ++o) acc[o] = 0.f;
  for (int c = 0; c < D; ++c) {
    float xc = col[c];
    const float* wr = Wg2Tf + c * D;
    #pragma unroll
    for (int o = 0; o < D; ++o) acc[o] = fmaf(wr[o], xc, acc[o]);
  }

  // softmax over K (16-lane groups) + weighted sum of (v + pos_enc)
  #pragma unroll
  for (int o = 0; o < D; ++o) {
    float t = lrelu(acc[o] + bg2[o]) * RSQN;
    float mx = t;
    mx = fmaxf(mx, __shfl_xor(mx, 1));
    mx = fmaxf(mx, __shfl_xor(mx, 2));
    mx = fmaxf(mx, __shfl_xor(mx, 4));
    mx = fmaxf(mx, __shfl_xor(mx, 8));
    float e = __expf(t - mx);
    float s = e;
    s += __shfl_xor(s, 1);
    s += __shfl_xor(s, 2);
    s += __shfl_xor(s, 4);
    s += __shfl_xor(s, 8);
    float r = (e / s) * vpe[o];
    r += __shfl_xor(r, 1);
    r += __shfl_xor(r, 2);
    r += __shfl_xor(r, 4);
    r += __shfl_xor(r, 8);
    acc[o] = r;                       // res, replicated across the 16 lanes
  }

  // out = lrelu(bn(W2 @ res)) + feats ; each lane writes channels o = kk*4 + j
  const float* fb = feats + (size_t)b * D * N + n;
  float* ob = out + (size_t)b * D * N + n;
  #pragma unroll
  for (int j = 0; j < 4; ++j) {
    int o = kk * 4 + j;
    const float* wrow = W2f + o * D;
    float a = 0.f;
    #pragma unroll
    for (int c = 0; c < D; ++c) a = fmaf(wrow[c], acc[c], a);
    float v = lrelu(a + b2[o]);
    ob[(size_t)o * N] = v + fb[(size_t)o * N];
  }
}

} // namespace

extern "C" void kernel_launch(void* const* d_in, const int* in_sizes, int n_in,
                              void* d_out, int out_size, void* d_ws, size_t ws_size,
                              hipStream_t stream) {
  const float* feats = (const float*)d_in[0];
  const float* pos   = (const float*)d_in[1];
  const float* W1  = (const float*)d_in[3];
  const float* g1  = (const float*)d_in[4];
  const float* b1  = (const float*)d_in[5];
  const float* Wq  = (const float*)d_in[6];
  const float* Wk  = (const float*)d_in[7];
  const float* Wv  = (const float*)d_in[8];
  const float* Wd1 = (const float*)d_in[9];
  const float* gd1 = (const float*)d_in[10];
  const float* bd1 = (const float*)d_in[11];
  const float* Wd2 = (const float*)d_in[12];
  const float* gd2 = (const float*)d_in[13];
  const float* bd2 = (const float*)d_in[14];
  const float* Wg1 = (const float*)d_in[15];
  const float* gg1 = (const float*)d_in[16];
  const float* bg1 = (const float*)d_in[17];
  const float* Wg2 = (const float*)d_in[18];
  const float* gg2 = (const float*)d_in[19];
  const float* bg2 = (const float*)d_in[20];
  const float* W2  = (const float*)d_in[21];
  const float* g2  = (const float*)d_in[22];
  const float* b2  = (const float*)d_in[23];

  float* ws = (float*)d_ws;
  float* W1Tf  = ws;
  float* WqT   = ws + 4096;
  float* WkT   = ws + 8192;
  float* WvT   = ws + 12288;
  float* Wd2Tf = ws + 16384;
  float* Wg1Tf = ws + 20480;
  float* Wg2Tf = ws + 24576;
  float* W2f   = ws + 28672;
  float* Wd1f  = ws + 32768;            // 256
  float* qT = ws + 33024;
  float* kT = qT + (size_t)B * N * D;
  float* vT = kT + (size_t)B * N * D;
  float* pos4 = vT + (size_t)B * N * D;                     // B*N*4
  float* pd  = pos4 + (size_t)B * N * 4;                    // B*N*PART*16
  int*   pi  = (int*)(pd + (size_t)B * N * PART * 16);      // B*N*PART*16
  float* pd2 = (float*)(pi + (size_t)B * N * PART * 16);    // B*N*2*16
  int*   pi2 = (int*)(pd2 + (size_t)B * N * 2 * 16);        // B*N*2*16
  int*   knn = pi2 + (size_t)B * N * 2 * 16;                // B*N*16

  PrepArgs pa;
  pa.src[0] = W1;  pa.scale[0] = g1;      pa.dst[0] = W1Tf;
  pa.src[1] = Wq;  pa.scale[1] = nullptr; pa.dst[1] = WqT;
  pa.src[2] = Wk;  pa.scale[2] = nullptr; pa.dst[2] = WkT;
  pa.src[3] = Wv;  pa.scale[3] = nullptr; pa.dst[3] = WvT;
  pa.src[4] = Wd2; pa.scale[4] = gd2;     pa.dst[4] = Wd2Tf;
  pa.src[5] = Wg1; pa.scale[5] = gg1;     pa.dst[5] = Wg1Tf;
  pa.src[6] = Wg2; pa.scale[6] = gg2;     pa.dst[6] = Wg2Tf;
  pa.src[7] = W2;  pa.scale[7] = g2;      pa.dst[7] = W2f;
  pa.src[8] = Wd1; pa.scale[8] = gd1;     pa.dst[8] = Wd1f;

  hipLaunchKernelGGL(prep_kernel, dim3(9), dim3(256), 0, stream, pa);
  hipLaunchKernelGGL(pos4_kernel, dim3(B * N / 256), dim3(256), 0, stream, pos, pos4);
  hipLaunchKernelGGL(qkv_kernel, dim3(B * N / 64), dim3(64), 0, stream,
                     feats, W1Tf, b1, WqT, WkT, WvT, qT, kT, vT);
  hipLaunchKernelGGL(knn_kernel, dim3(B * N / 256, PART), dim3(256), 0, stream,
                     pos4, pd, pi);
  hipLaunchKernelGGL(merge4_kernel, dim3(B * N * 2 / 256), dim3(256), 0, stream,
                     pd, pi, pd2, pi2);
  hipLaunchKernelGGL(merge2_kernel, dim3(B * N / 256), dim3(256), 0, stream,
                     pd2, pi2, knn);
  hipLaunchKernelGGL(fused_kernel, dim3(B * N / 4), dim3(64), 0, stream,
                     pos, feats, knn, qT, kT, vT, Wd1f, bd1, Wd2Tf, bd2,
                     Wg1Tf, bg1, Wg2Tf, bg2, W2f, b2, (float*)d_out);
}

// Round 3
// 287.331 us; speedup vs baseline: 4.2914x; 1.6976x over previous
//
#include <hip/hip_runtime.h>
#include <hip/hip_bf16.h>
#include <math.h>

namespace {

constexpr int B = 2;
constexpr int N = 8192;
constexpr int PART = 8;
constexpr int CAND = N / PART;          // 1024
constexpr int BUF = 16;
constexpr int D = 64;
constexpr float NEGS = 0.2f;
constexpr float BN_INV = 0.9999950000374997f;   // 1/sqrt(1+1e-5)
constexpr float RSQN = 0.011048543456039806f;   // 1/sqrt(8192)

typedef __attribute__((ext_vector_type(8))) short bf16x8;
typedef __attribute__((ext_vector_type(16))) float f32x16;

union Frag { int4 i4; unsigned u[4]; bf16x8 h; };

__device__ __forceinline__ float lrelu(float v) { return v > 0.f ? v : NEGS * v; }

__device__ __forceinline__ unsigned pk2(float a, float b) {
  __hip_bfloat162 h2 = __float22bfloat162_rn(make_float2(a, b));
  unsigned r;
  __builtin_memcpy(&r, &h2, 4);
  return r;
}
__device__ __forceinline__ float blo(unsigned u) { return __uint_as_float(u << 16); }
__device__ __forceinline__ float bhi(unsigned u) { return __uint_as_float(u & 0xFFFF0000u); }

__device__ __forceinline__ f32x16 MF(int4 a, const Frag& b, f32x16 c) {
  Frag af; af.i4 = a;
  return __builtin_amdgcn_mfma_f32_32x32x16_bf16(af.h, b.h, c, 0, 0, 0);
}

// D-layout f32 (x0: chans 0-31 rows, x1: chans 32-63) -> B-fragments for next layer.
// D: chan = 32mt + 8q + 4h + j  (q=reg>>2, j=reg&3, h=lane>>5)
// B: frag t holds chans 16t + 8h + i, i=0..7 (k-contiguous per lane)
__device__ __forceinline__ void buildB(const f32x16& x0, const f32x16& x1, int h, Frag Bf[4]) {
  unsigned Z[8][2];
  #pragma unroll
  for (int q = 0; q < 4; ++q) {
    Z[q][0]     = pk2(x0[4*q+0], x0[4*q+1]);
    Z[q][1]     = pk2(x0[4*q+2], x0[4*q+3]);
    Z[4+q][0]   = pk2(x1[4*q+0], x1[4*q+1]);
    Z[4+q][1]   = pk2(x1[4*q+2], x1[4*q+3]);
  }
  unsigned S[8][2];
  #pragma unroll
  for (int q = 0; q < 8; ++q) {
    S[q][0] = (unsigned)__shfl_xor((int)Z[q][0], 32);
    S[q][1] = (unsigned)__shfl_xor((int)Z[q][1], 32);
  }
  #pragma unroll
  for (int t = 0; t < 4; ++t) {
    int qq = (t >> 1) * 4 + 2 * (t & 1);
    Bf[t].u[0] = h ? S[qq+1][0] : Z[qq][0];
    Bf[t].u[1] = h ? S[qq+1][1] : Z[qq][1];
    Bf[t].u[2] = h ? Z[qq+1][0] : S[qq][0];
    Bf[t].u[3] = h ? Z[qq+1][1] : S[qq][1];
  }
}

// bias (pre-permuted [h][mt][q][j]) + leaky relu
__device__ __forceinline__ f32x16 biasAct(f32x16 d, const float4* bp, int mt, int h) {
  f32x16 r;
  #pragma unroll
  for (int q = 0; q < 4; ++q) {
    float4 bb = bp[h * 8 + mt * 4 + q];
    r[4*q+0] = lrelu(d[4*q+0] + bb.x);
    r[4*q+1] = lrelu(d[4*q+1] + bb.y);
    r[4*q+2] = lrelu(d[4*q+2] + bb.z);
    r[4*q+3] = lrelu(d[4*q+3] + bb.w);
  }
  return r;
}

// ---------------- prep: pack A-fragments (bf16, BN scale folded) + permuted biases ----------------
struct PrepArgs {
  const float* W[9];       // W1,Wq,Wk,Wv,Wd2,Wg1,Wg2,W2,Wd1
  const float* scale[9];
  const float* bias[5];    // b1,bd2,bg1,bg2,b2
  const float* bd1;
};

__global__ __launch_bounds__(256) void prep_kernel(PrepArgs a, unsigned short* AF, float* biasAll) {
  int mi = blockIdx.x;
  int tid = threadIdx.x;
  if (mi < 8) {
    // square matrices; AF elem offsets: W1 0, Wq 4096, Wk 8192, Wv 12288, Wd2 16384, Wg1 20480, Wg2 24576, W2 29696
    int off = (mi == 7) ? 29696 : mi * 4096;
    const float* W = a.W[mi];
    const float* G = a.scale[mi];
    unsigned short* dst = AF + off;
    for (int e = tid; e < 4096; e += 256) {
      int i = e & 7, lane = (e >> 3) & 63, t = (e >> 9) & 3, mt = e >> 11;
      int row = 32 * mt + (lane & 31);
      int k = 16 * t + 8 * (lane >> 5) + i;
      float v = W[row * 64 + k];
      if (G) v *= G[row] * BN_INV;
      __hip_bfloat16 hb = __float2bfloat16(v);
      __builtin_memcpy(&dst[e], &hb, 2);
    }
  } else {
    // Wd1A at elem 28672: K=16 tile, only h==0 k<4 used ([wd1*s | bd1])
    const float* W = a.W[8];
    const float* G = a.scale[8];
    for (int e = tid; e < 1024; e += 256) {
      int i = e & 7, lane = (e >> 3) & 63, mt = e >> 9;
      int row = 32 * mt + (lane & 31), h = lane >> 5;
      float v = 0.f;
      if (h == 0) {
        if (i < 3) v = W[row * 3 + i] * G[row] * BN_INV;
        else if (i == 3) v = a.bd1[row];
      }
      __hip_bfloat16 hb = __float2bfloat16(v);
      __builtin_memcpy(&AF[28672 + e], &hb, 2);
    }
    for (int e = tid; e < 320; e += 256) {
      int ai = e >> 6, idx = e & 63;
      int h = idx >> 5, mt = (idx >> 4) & 1, q = (idx >> 2) & 3, j = idx & 3;
      biasAll[e] = a.bias[ai][32 * mt + 8 * q + 4 * h + j];
    }
  }
}

// ---------------- pos4: pack (x,y,z,|p|^2) ----------------
__global__ __launch_bounds__(256) void pos4_kernel(
    const float* __restrict__ pos, float* __restrict__ pos4)
{
  int i = blockIdx.x * 256 + threadIdx.x;
  int b = i >> 13;
  int n = i & (N - 1);
  const float* pb = pos + (size_t)b * 3 * N;
  float x = pb[n], y = pb[N + n], z = pb[2 * N + n];
  float4 v = {x, y, z, x * x + y * y + z * z};
  *reinterpret_cast<float4*>(pos4 + (size_t)i * 4) = v;
}

// ---------------- qkv (MFMA): X = lrelu(bn(W1@feats)); q/k/v = W@X stored bf16 [pt][64] ----------------
__global__ __launch_bounds__(256) void qkv_kernel(
    const float* __restrict__ feats, const int4* __restrict__ AF,
    const float* __restrict__ b1p,
    uint2* __restrict__ qT, uint2* __restrict__ kT, uint2* __restrict__ vT)
{
  __shared__ int4 sA[2048];   // W1 | Wq | Wk | Wv
  for (int i = threadIdx.x; i < 2048; i += 256) sA[i] = AF[i];
  __syncthreads();
  int lane = threadIdx.x & 63, w = threadIdx.x >> 6;
  int gw = blockIdx.x * 4 + w;
  int col = lane & 31, h = lane >> 5;
  int nb = gw * 32;
  int b = nb >> 13;
  int n = (nb & (N - 1)) + col;
  size_t gpt = (size_t)b * N + n;
  const float* fb = feats + (size_t)b * D * N + n;

  Frag Bf[4];
  #pragma unroll
  for (int t = 0; t < 4; ++t) {
    int c0 = 16 * t + 8 * h;
    float f[8];
    #pragma unroll
    for (int i = 0; i < 8; ++i) f[i] = fb[(size_t)(c0 + i) * N];
    #pragma unroll
    for (int d_ = 0; d_ < 4; ++d_) Bf[t].u[d_] = pk2(f[2*d_], f[2*d_+1]);
  }
  f32x16 acc0 = {}, acc1 = {};
  #pragma unroll
  for (int t = 0; t < 4; ++t) {
    acc0 = MF(sA[t * 64 + lane], Bf[t], acc0);
    acc1 = MF(sA[(4 + t) * 64 + lane], Bf[t], acc1);
  }
  const float4* bp = (const float4*)b1p;
  f32x16 x0 = biasAct(acc0, bp, 0, h);
  f32x16 x1 = biasAct(acc1, bp, 1, h);
  Frag Bx[4];
  buildB(x0, x1, h, Bx);

  #pragma unroll
  for (int mmat = 0; mmat < 3; ++mmat) {
    const int4* Am = sA + 512 * (mmat + 1);
    uint2* op = (mmat == 0) ? qT : (mmat == 1) ? kT : vT;
    f32x16 a0 = {}, a1 = {};
    #pragma unroll
    for (int t = 0; t < 4; ++t) {
      a0 = MF(Am[t * 64 + lane], Bx[t], a0);
      a1 = MF(Am[(4 + t) * 64 + lane], Bx[t], a1);
    }
    #pragma unroll
    for (int q = 0; q < 4; ++q) {
      uint2 v0, v1;
      v0.x = pk2(a0[4*q+0], a0[4*q+1]); v0.y = pk2(a0[4*q+2], a0[4*q+3]);
      v1.x = pk2(a1[4*q+0], a1[4*q+1]); v1.y = pk2(a1[4*q+2], a1[4*q+3]);
      op[gpt * 16 + 2 * q + h] = v0;
      op[gpt * 16 + 8 + 2 * q + h] = v1;
    }
  }
}

// ---------------- knn: buffered top-16 per (query, partition) ----------------
__global__ __launch_bounds__(256) void knn_kernel(
    const float* __restrict__ pos4,
    float* __restrict__ pd, int* __restrict__ pi)
{
  __shared__ float bufd[256 * BUF];
  __shared__ int   bufi[256 * BUF];
  int tid = threadIdx.x;
  int b = blockIdx.x >> 5;
  int n = (blockIdx.x & 31) * 256 + tid;
  int q = b * N + n;
  int p = blockIdx.y;
  const float* base = pos4 + (size_t)b * N * 4;
  float4 qp = *reinterpret_cast<const float4*>(base + (size_t)n * 4);

  float d[16];
  int id[16];
  #pragma unroll
  for (int j = 0; j < 16; ++j) { d[j] = 3.4e38f; id[j] = -1; }
  float thr = 3.4e38f;
  int c = 0;

  auto do_merge = [&]() {
    #pragma unroll 1
    for (int t = 0; t < BUF; ++t) {
      if (__all(t >= c)) break;
      float nd = 3.5e38f;
      int ni = -1;
      if (t < c) {
        nd = bufd[tid + (t << 8)];
        ni = bufi[tid + (t << 8)];
      }
      if (nd < d[15]) {
        bool bj = true;
        #pragma unroll
        for (int j = 15; j >= 1; --j) {
          bool bjm1 = nd < d[j - 1];
          d[j]  = bj ? (bjm1 ? d[j - 1]  : nd) : d[j];
          id[j] = bj ? (bjm1 ? id[j - 1] : ni) : id[j];
          bj = bjm1;
        }
        if (bj) { d[0] = nd; id[0] = ni; }
      }
    }
    c = 0;
    thr = d[15];
  };

  int mbase = p * CAND;
  #pragma unroll 1
  for (int m0 = mbase; m0 < mbase + CAND; m0 += 4) {
    #pragma unroll
    for (int u = 0; u < 4; ++u) {
      int mm = m0 + u;
      const float4 cp = *reinterpret_cast<const float4*>(base + (size_t)mm * 4);
      float inn = qp.x * cp.x + qp.y * cp.y + qp.z * cp.z;
      float dist = fmaf(-2.f, inn, qp.w + cp.w);
      if (dist < thr) {
        bufd[tid + (c << 8)] = dist;
        bufi[tid + (c << 8)] = mm;
        ++c;
      }
    }
    if (__any(c >= BUF - 3)) do_merge();
  }
  do_merge();

  float* od = pd + ((size_t)q * PART + p) * 16;
  int* oi = pi + ((size_t)q * PART + p) * 16;
  #pragma unroll
  for (int j = 0; j < 16; ++j) { od[j] = d[j]; oi[j] = id[j]; }
}

// ---------------- merge stage 1: 4 sorted lists -> 1 (x2 groups per query) ----------------
__global__ __launch_bounds__(256) void merge4_kernel(
    const float* __restrict__ pd, const int* __restrict__ pi,
    float* __restrict__ pd2, int* __restrict__ pi2)
{
  int i = blockIdx.x * 256 + threadIdx.x;
  const float* base = pd + (size_t)i * 64;
  const int* ibase = pi + (size_t)i * 64;
  float* od = pd2 + (size_t)i * 16;
  int* oi = pi2 + (size_t)i * 16;
  int c0 = 0, c1 = 0, c2 = 0, c3 = 0;
  #pragma unroll 1
  for (int r = 0; r < 16; ++r) {
    float d0 = (c0 < 16) ? base[c0]      : 3.5e38f;
    float d1 = (c1 < 16) ? base[16 + c1] : 3.5e38f;
    float d2 = (c2 < 16) ? base[32 + c2] : 3.5e38f;
    float d3 = (c3 < 16) ? base[48 + c3] : 3.5e38f;
    int bp = 0; float bd = d0;
    if (d1 < bd) { bd = d1; bp = 1; }
    if (d2 < bd) { bd = d2; bp = 2; }
    if (d3 < bd) { bd = d3; bp = 3; }
    float sd; int sel;
    if (bp == 0)      { sd = d0; sel = ibase[c0];      c0++; }
    else if (bp == 1) { sd = d1; sel = ibase[16 + c1]; c1++; }
    else if (bp == 2) { sd = d2; sel = ibase[32 + c2]; c2++; }
    else              { sd = d3; sel = ibase[48 + c3]; c3++; }
    od[r] = sd;
    oi[r] = sel;
  }
}

// ---------------- merge stage 2: 2 sorted lists -> final 16 ----------------
__global__ __launch_bounds__(256) void merge2_kernel(
    const float* __restrict__ pd2, const int* __restrict__ pi2, int* __restrict__ knn)
{
  int q = blockIdx.x * 256 + threadIdx.x;
  const float* base = pd2 + (size_t)q * 32;
  const int* ibase = pi2 + (size_t)q * 32;
  int c0 = 0, c1 = 0;
  #pragma unroll 1
  for (int r = 0; r < 16; ++r) {
    float d0 = (c0 < 16) ? base[c0]      : 3.5e38f;
    float d1 = (c1 < 16) ? base[16 + c1] : 3.5e38f;
    int sel;
    if (d1 < d0) { sel = ibase[16 + c1]; c1++; }
    else         { sel = ibase[c0];      c0++; }
    knn[(size_t)q * 16 + r] = sel;
  }
}

// ---------------- fused (MFMA): pe -> pos_enc -> a0 -> a1 -> a2 -> softmax -> res ----------------
__global__ __launch_bounds__(256) void fused_kernel(
    const float4* __restrict__ pos4, const int* __restrict__ knn,
    const uint2* __restrict__ qT, const uint2* __restrict__ kT, const uint2* __restrict__ vT,
    const int4* __restrict__ AF,      // [Wd2 | Wg1 | Wg2 | Wd1]
    const float* __restrict__ biases, // bd2p | bg1p | bg2p
    float* __restrict__ res_ws)
{
  __shared__ int4 sA[1664];
  for (int i = threadIdx.x; i < 1664; i += 256) sA[i] = AF[i];
  __syncthreads();
  const float4* bpd2 = (const float4*)(biases);
  const float4* bpg1 = (const float4*)(biases + 64);
  const float4* bpg2 = (const float4*)(biases + 128);

  int lane = threadIdx.x & 63, w = threadIdx.x >> 6;
  int gw = blockIdx.x * 4 + w;
  int col = lane & 31, h = lane >> 5;
  int p = col >> 4, kk = col & 15;
  int pbase = gw * 2;
  int b = pbase >> 13;
  int n = (pbase & (N - 1)) + p;
  size_t g = (size_t)b * N + n;
  int m = knn[g * 16 + kk];
  size_t gm = (size_t)b * N + m;

  float4 P = pos4[g], Q = pos4[gm];
  float rx = P.x - Q.x, ry = P.y - Q.y, rz = P.z - Q.z;

  // L0: pe = lrelu(s*Wd1@rel + bd1)   (bias via B k=3 column)
  Frag B0;
  B0.u[0] = h ? 0u : pk2(rx, ry);
  B0.u[1] = h ? 0u : pk2(rz, 1.0f);
  B0.u[2] = 0u; B0.u[3] = 0u;
  f32x16 acc0 = {}, acc1 = {};
  acc0 = MF(sA[1536 + lane], B0, acc0);
  acc1 = MF(sA[1536 + 64 + lane], B0, acc1);
  f32x16 pe0, pe1;
  #pragma unroll
  for (int i = 0; i < 16; ++i) { pe0[i] = lrelu(acc0[i]); pe1[i] = lrelu(acc1[i]); }
  Frag Bp[4];
  buildB(pe0, pe1, h, Bp);

  // L1: pos_enc = lrelu(s*Wd2@pe + bd2)
  acc0 = (f32x16){}; acc1 = (f32x16){};
  #pragma unroll
  for (int t = 0; t < 4; ++t) {
    acc0 = MF(sA[t * 64 + lane], Bp[t], acc0);
    acc1 = MF(sA[(4 + t) * 64 + lane], Bp[t], acc1);
  }
  f32x16 pn0 = biasAct(acc0, bpd2, 0, h);
  f32x16 pn1 = biasAct(acc1, bpd2, 1, h);

  // keep pos_enc packed (bf16 pairs) for vpe
  unsigned pep[8][2];
  #pragma unroll
  for (int q = 0; q < 4; ++q) {
    pep[q][0]   = pk2(pn0[4*q+0], pn0[4*q+1]);
    pep[q][1]   = pk2(pn0[4*q+2], pn0[4*q+3]);
    pep[4+q][0] = pk2(pn1[4*q+0], pn1[4*q+1]);
    pep[4+q][1] = pk2(pn1[4*q+2], pn1[4*q+3]);
  }

  // a0 = q[n] - k[m] + pos_enc
  f32x16 av0, av1;
  #pragma unroll
  for (int mt = 0; mt < 2; ++mt) {
    f32x16& dst = mt ? av1 : av0;
    const f32x16& pn = mt ? pn1 : pn0;
    #pragma unroll
    for (int q = 0; q < 4; ++q) {
      uint2 qv = qT[g * 16 + 8 * mt + 2 * q + h];
      uint2 kv = kT[gm * 16 + 8 * mt + 2 * q + h];
      dst[4*q+0] = pn[4*q+0] + blo(qv.x) - blo(kv.x);
      dst[4*q+1] = pn[4*q+1] + bhi(qv.x) - bhi(kv.x);
      dst[4*q+2] = pn[4*q+2] + blo(qv.y) - blo(kv.y);
      dst[4*q+3] = pn[4*q+3] + bhi(qv.y) - bhi(kv.y);
    }
  }
  buildB(av0, av1, h, Bp);

  // L2: a1 = lrelu(s*Wg1@a0 + bg1)
  acc0 = (f32x16){}; acc1 = (f32x16){};
  #pragma unroll
  for (int t = 0; t < 4; ++t) {
    acc0 = MF(sA[512 + t * 64 + lane], Bp[t], acc0);
    acc1 = MF(sA[512 + (4 + t) * 64 + lane], Bp[t], acc1);
  }
  f32x16 a10 = biasAct(acc0, bpg1, 0, h);
  f32x16 a11 = biasAct(acc1, bpg1, 1, h);
  buildB(a10, a11, h, Bp);

  // L3: a2 = lrelu(s*Wg2@a1 + bg2) * RSQN
  acc0 = (f32x16){}; acc1 = (f32x16){};
  #pragma unroll
  for (int t = 0; t < 4; ++t) {
    acc0 = MF(sA[1024 + t * 64 + lane], Bp[t], acc0);
    acc1 = MF(sA[1024 + (4 + t) * 64 + lane], Bp[t], acc1);
  }
  f32x16 at0 = biasAct(acc0, bpg2, 0, h);
  f32x16 at1 = biasAct(acc1, bpg2, 1, h);
  #pragma unroll
  for (int i = 0; i < 16; ++i) { at0[i] *= RSQN; at1[i] *= RSQN; }

  // softmax over kk (values are tiny: |a2*RSQN| << 1, so no max-subtraction needed)
  // and weighted sum of vpe = v + pos_enc;  res = (sum e*vpe) / (sum e)
  float* rp = res_ws + g * 64;
  #pragma unroll
  for (int mt = 0; mt < 2; ++mt) {
    const f32x16& at = mt ? at1 : at0;
    f32x16 ev, nm;
    #pragma unroll
    for (int q = 0; q < 4; ++q) {
      uint2 vv = vT[gm * 16 + 8 * mt + 2 * q + h];
      unsigned pp0 = pep[mt * 4 + q][0], pp1 = pep[mt * 4 + q][1];
      float vp0 = blo(vv.x) + blo(pp0);
      float vp1 = bhi(vv.x) + bhi(pp0);
      float vp2 = blo(vv.y) + blo(pp1);
      float vp3 = bhi(vv.y) + bhi(pp1);
      ev[4*q+0] = __expf(at[4*q+0]); nm[4*q+0] = ev[4*q+0] * vp0;
      ev[4*q+1] = __expf(at[4*q+1]); nm[4*q+1] = ev[4*q+1] * vp1;
      ev[4*q+2] = __expf(at[4*q+2]); nm[4*q+2] = ev[4*q+2] * vp2;
      ev[4*q+3] = __expf(at[4*q+3]); nm[4*q+3] = ev[4*q+3] * vp3;
    }
    #pragma unroll
    for (int i = 0; i < 16; ++i) {
      #pragma unroll
      for (int mask = 1; mask <= 8; mask <<= 1) {
        ev[i] += __shfl_xor(ev[i], mask);
        nm[i] += __shfl_xor(nm[i], mask);
      }
    }
    if (kk == 0) {
      #pragma unroll
      for (int q = 0; q < 4; ++q) {
        float4 r;
        r.x = nm[4*q+0] / ev[4*q+0];
        r.y = nm[4*q+1] / ev[4*q+1];
        r.z = nm[4*q+2] / ev[4*q+2];
        r.w = nm[4*q+3] / ev[4*q+3];
        *(float4*)(rp + 32 * mt + 8 * q + 4 * h) = r;
      }
    }
  }
}

// ---------------- final (MFMA): out = lrelu(bn(W2@res)) + feats ----------------
__global__ __launch_bounds__(256) void final_kernel(
    const float* __restrict__ res_ws, const int4* __restrict__ AF,
    const float* __restrict__ b2p, const float* __restrict__ feats,
    float* __restrict__ out)
{
  __shared__ int4 sA[512];
  for (int i = threadIdx.x; i < 512; i += 256) sA[i] = AF[i];
  __syncthreads();
  int lane = threadIdx.x & 63, w = threadIdx.x >> 6;
  int gw = blockIdx.x * 4 + w;
  int col = lane & 31, h = lane >> 5;
  int nb = gw * 32;
  int b = nb >> 13;
  int n = (nb & (N - 1)) + col;
  size_t g = (size_t)b * N + n;
  const float* rp = res_ws + g * 64;
  Frag Br[4];
  #pragma unroll
  for (int t = 0; t < 4; ++t) {
    float4 r0 = *(const float4*)(rp + 16 * t + 8 * h);
    float4 r1 = *(const float4*)(rp + 16 * t + 8 * h + 4);
    Br[t].u[0] = pk2(r0.x, r0.y); Br[t].u[1] = pk2(r0.z, r0.w);
    Br[t].u[2] = pk2(r1.x, r1.y); Br[t].u[3] = pk2(r1.z, r1.w);
  }
  f32x16 a0 = {}, a1 = {};
  #pragma unroll
  for (int t = 0; t < 4; ++t) {
    a0 = MF(sA[t * 64 + lane], Br[t], a0);
    a1 = MF(sA[(4 + t) * 64 + lane], Br[t], a1);
  }
  const float4* bp = (const float4*)b2p;
  f32x16 o0 = biasAct(a0, bp, 0, h);
  f32x16 o1 = biasAct(a1, bp, 1, h);
  const float* fb = feats + (size_t)b * D * N;
  float* ob = out + (size_t)b * D * N;
  #pragma unroll
  for (int mt = 0; mt < 2; ++mt) {
    const f32x16& oo = mt ? o1 : o0;
    #pragma unroll
    for (int q = 0; q < 4; ++q) {
      #pragma unroll
      for (int j = 0; j < 4; ++j) {
        int chan = 32 * mt + 8 * q + 4 * h + j;
        ob[(size_t)chan * N + n] = oo[4*q+j] + fb[(size_t)chan * N + n];
      }
    }
  }
}

} // namespace

extern "C" void kernel_launch(void* const* d_in, const int* in_sizes, int n_in,
                              void* d_out, int out_size, void* d_ws, size_t ws_size,
                              hipStream_t stream) {
  const float* feats = (const float*)d_in[0];
  const float* pos   = (const float*)d_in[1];
  const float* W1  = (const float*)d_in[3];
  const float* g1  = (const float*)d_in[4];
  const float* b1  = (const float*)d_in[5];
  const float* Wq  = (const float*)d_in[6];
  const float* Wk  = (const float*)d_in[7];
  const float* Wv  = (const float*)d_in[8];
  const float* Wd1 = (const float*)d_in[9];
  const float* gd1 = (const float*)d_in[10];
  const float* bd1 = (const float*)d_in[11];
  const float* Wd2 = (const float*)d_in[12];
  const float* gd2 = (const float*)d_in[13];
  const float* bd2 = (const float*)d_in[14];
  const float* Wg1 = (const float*)d_in[15];
  const float* gg1 = (const float*)d_in[16];
  const float* bg1 = (const float*)d_in[17];
  const float* Wg2 = (const float*)d_in[18];
  const float* gg2 = (const float*)d_in[19];
  const float* bg2 = (const float*)d_in[20];
  const float* W2  = (const float*)d_in[21];
  const float* g2  = (const float*)d_in[22];
  const float* b2  = (const float*)d_in[23];

  uint8_t* wsb = (uint8_t*)d_ws;
  unsigned short* AF = (unsigned short*)wsb;               // 33792 bf16 elems (reserve 73728 B)
  float* biasAll = (float*)(wsb + 73728);                  // 320 floats
  float* pos4    = (float*)(wsb + 75008);                  // 65536 floats (256 KB)
  uint2* qTb     = (uint2*)(wsb + 337152);                 // 2 MB
  uint2* kTb     = (uint2*)(wsb + 337152 + 2097152);       // 2 MB
  uint2* vTb     = (uint2*)(wsb + 337152 + 2*2097152);     // 2 MB
  float* res_ws  = (float*)(wsb + 6628608);                // 4 MB
  float* pd      = (float*)(wsb + 10822912);               // 8 MB
  int*   pi      = (int*)(wsb + 19211520);                 // 8 MB
  float* pd2     = (float*)(wsb + 27600128);               // 2 MB
  int*   pi2     = (int*)(wsb + 29697280);                 // 2 MB
  int*   knn     = (int*)(wsb + 31794432);                 // 2 MB

  PrepArgs pa;
  pa.W[0] = W1;  pa.W[1] = Wq;  pa.W[2] = Wk;  pa.W[3] = Wv;
  pa.W[4] = Wd2; pa.W[5] = Wg1; pa.W[6] = Wg2; pa.W[7] = W2; pa.W[8] = Wd1;
  pa.scale[0] = g1;  pa.scale[1] = nullptr; pa.scale[2] = nullptr; pa.scale[3] = nullptr;
  pa.scale[4] = gd2; pa.scale[5] = gg1;     pa.scale[6] = gg2;     pa.scale[7] = g2; pa.scale[8] = gd1;
  pa.bias[0] = b1; pa.bias[1] = bd2; pa.bias[2] = bg1; pa.bias[3] = bg2; pa.bias[4] = b2;
  pa.bd1 = bd1;

  hipLaunchKernelGGL(prep_kernel, dim3(9), dim3(256), 0, stream, pa, AF, biasAll);
  hipLaunchKernelGGL(pos4_kernel, dim3(B * N / 256), dim3(256), 0, stream, pos, pos4);
  hipLaunchKernelGGL(qkv_kernel, dim3(128), dim3(256), 0, stream,
                     feats, (const int4*)wsb, biasAll, qTb, kTb, vTb);
  hipLaunchKernelGGL(knn_kernel, dim3(B * N / 256, PART), dim3(256), 0, stream,
                     pos4, pd, pi);
  hipLaunchKernelGGL(merge4_kernel, dim3(B * N * 2 / 256), dim3(256), 0, stream,
                     pd, pi, pd2, pi2);
  hipLaunchKernelGGL(merge2_kernel, dim3(B * N / 256), dim3(256), 0, stream,
                     pd2, pi2, knn);
  hipLaunchKernelGGL(fused_kernel, dim3(2048), dim3(256), 0, stream,
                     (const float4*)pos4, knn, qTb, kTb, vTb,
                     (const int4*)(wsb + 32768), biasAll + 64, res_ws);
  hipLaunchKernelGGL(final_kernel, dim3(128), dim3(256), 0, stream,
                     res_ws, (const int4*)(wsb + 59392), biasAll + 256, feats, (float*)d_out);
}